// Round 9
// baseline (371.268 us; speedup 1.0000x reference)
//
#include <hip/hip_runtime.h>
#include <hip/hip_bf16.h>
#include <stdint.h>

typedef __attribute__((ext_vector_type(8))) short s8v;   // 8 bf16 = K32 MFMA A/B frag
typedef __attribute__((ext_vector_type(4))) float f4v;   // MFMA C/D frag

#define NE   128
#define NT   2048
#define DIN  128
#define DH   512
#define DOUT 128

#define MFMA32(a,b,c) __builtin_amdgcn_mfma_f32_16x16x32_bf16(a,b,c,0,0,0)
// NOTE: stage2 no longer uses the gfx90a-era 16x16x16_1k builtin. Round-7
// counters implied ~21 cyc/instr for it on gfx950 (MfmaUtil 30% at known
// instruction counts) vs 4.85 cyc for the native K32 op — stage2 now runs
// K=32 with a sigma-permuted W2 pack so the gelu outputs feed it directly.

// async global->LDS, 16B per lane; LDS dest must be wave-uniform base + lane*16
#define GLOAD16(g,l) __builtin_amdgcn_global_load_lds( \
    (const __attribute__((address_space(1))) void*)(g), \
    (__attribute__((address_space(3))) void*)(l), 16, 0, 0)

#define WAIT_VM(N) asm volatile("s_waitcnt vmcnt(" #N ")" ::: "memory")
// raw barrier (no implicit vmcnt(0) drain, unlike __syncthreads)
#define BAR() do { asm volatile("" ::: "memory"); \
                   __builtin_amdgcn_s_barrier();  \
                   asm volatile("" ::: "memory"); } while (0)

__device__ __forceinline__ __hip_bfloat162 pk2(float a, float b) {
  float2 t; t.x = a; t.y = b;
  return __float22bfloat162_rn(t);
}

__device__ __forceinline__ s8v pack8(float4 a, float4 b) {
  union { s8v v; __hip_bfloat162 h[4]; } u;
  u.h[0] = pk2(a.x, a.y); u.h[1] = pk2(a.z, a.w);
  u.h[2] = pk2(b.x, b.y); u.h[3] = pk2(b.z, b.w);
  return u.v;
}

// gelu(x) = x * sigmoid(x*(1.5957691 + 0.07135481*x^2))  (tanh-form rewritten)
__device__ __forceinline__ float gelu_f(float x) {
  float x2 = x * x;
  float p  = __builtin_fmaf(x2, 0.07135481f, 1.5957691f);
  float e  = __expf(-x * p);
  return x * __builtin_amdgcn_rcpf(1.0f + e);
}

__device__ __forceinline__ float4 gelu4(f4v v) {
  float4 r;
  r.x = gelu_f(v[0]); r.y = gelu_f(v[1]);
  r.z = gelu_f(v[2]); r.w = gelu_f(v[3]);
  return r;
}

// ---------------- merged prep kernel ----------------
// Grid = NE*4 (W1 path) + NE*16 (W2 path).
//
// W1 path: block=(e,ks) reads rows d in [32ks,32ks+32) contiguously,
// transposes through LDS in 4 h-chunks of 128.
// W1F layout: [e][ht 0..31][ks 0..3][lane 0..63][8 bf16]; frag value j =
// W1[e][d = ks*32 + (lane>>4)*8 + j][h = ht*16 + (lane&15)]
//
// W2 path (K32 stage2): block=(e,ct) reads rows h in [32ct,32ct+32)
// contiguously. Output is a K32 B-frag with the sigma-permuted k order:
// position k = 8q+j holds h = 32ct + sigma_q(j),
//   sigma_q(j) = (j<4) ? 4q+j : 16+4q+(j-4)
// which is exactly where stage1's gelu outputs sit per lane (hl=0 gives
// h=4q+r, hl=1 gives h=16+4q+r). sigma is a bijection on [0,32) and both
// MFMA operands use the same permutation, so the contraction is exact.
// W2F layout: [e][ct 0..15][ot 0..7][lane 0..63][8 bf16]; frag value j =
// W2[e][h = 32ct + sigma_q(j)][o = ot*16 + (lane&15)]
#define W1_BLOCKS (NE * 4)
#define W2_BLOCKS (NE * 16)
__global__ __launch_bounds__(256) void pack_weights(
    const float* __restrict__ W1, const float* __restrict__ W2,
    ushort* __restrict__ W1F, ushort* __restrict__ W2F) {
  __shared__ __align__(16) float T[32 * 132];   // 16.9 KB, shared by both paths
  const int tid = threadIdx.x;
  const int lane = tid & 63, wid = tid >> 6;
  const int q = lane >> 4, l16 = lane & 15;

  if ((int)blockIdx.x < W1_BLOCKS) {
    const int e = blockIdx.x >> 2, ks = blockIdx.x & 3;
    const float* We = W1 + (size_t)e * (DIN * DH) + (size_t)(ks * 32) * DH;
    const int r = tid >> 3, c0 = (tid & 7) * 16;   // contiguous 64B/thread
    for (int hc = 0; hc < 4; ++hc) {
      if (hc) __syncthreads();                    // T reuse: reads done before rewrite
      const float* src = We + (size_t)r * DH + hc * 128 + c0;
      float4 v0 = *(const float4*)(src + 0);
      float4 v1 = *(const float4*)(src + 4);
      float4 v2 = *(const float4*)(src + 8);
      float4 v3 = *(const float4*)(src + 12);
      float* t = &T[r * 132 + c0];
      *(float4*)(t + 0) = v0; *(float4*)(t + 4)  = v1;
      *(float4*)(t + 8) = v2; *(float4*)(t + 12) = v3;
      __syncthreads();
#pragma unroll
      for (int i = 0; i < 2; ++i) {
        const int htl = wid + 4 * i;              // 0..7
        const int ht  = hc * 8 + htl;
        float g[8];
#pragma unroll
        for (int j = 0; j < 8; ++j) g[j] = T[(8 * q + j) * 132 + 16 * htl + l16];
        float4 a; a.x = g[0]; a.y = g[1]; a.z = g[2]; a.w = g[3];
        float4 b; b.x = g[4]; b.y = g[5]; b.z = g[6]; b.w = g[7];
        *(s8v*)(W1F + ((((size_t)e * 32 + ht) * 4) + ks) * 512 + lane * 8) = pack8(a, b);
      }
    }
  } else {
    const int bb = (int)blockIdx.x - W1_BLOCKS;
    const int e = bb >> 4, ct = bb & 15;
    const int r = tid >> 3, c0 = (tid & 7) * 16;   // contiguous 64B/thread
    const float* src = W2 + (size_t)e * (DH * DOUT) + (size_t)(ct * 32 + r) * DOUT + c0;
    float4 v0 = *(const float4*)(src + 0);
    float4 v1 = *(const float4*)(src + 4);
    float4 v2 = *(const float4*)(src + 8);
    float4 v3 = *(const float4*)(src + 12);
    float* t = &T[r * 132 + c0];
    *(float4*)(t + 0) = v0; *(float4*)(t + 4)  = v1;
    *(float4*)(t + 8) = v2; *(float4*)(t + 12) = v3;
    __syncthreads();
#pragma unroll
    for (int i = 0; i < 2; ++i) {
      const int ot = wid + 4 * i;                 // 0..7
      float g[8];
#pragma unroll
      for (int j = 0; j < 8; ++j) {
        const int sig = (j < 4) ? (4 * q + j) : (16 + 4 * q + (j - 4));
        g[j] = T[sig * 132 + ot * 16 + l16];
      }
      float4 a; a.x = g[0]; a.y = g[1]; a.z = g[2]; a.w = g[3];
      float4 b; b.x = g[4]; b.y = g[5]; b.z = g[6]; b.w = g[7];
      *(s8v*)(W2F + (((size_t)e * 16 + ct) * 8 + ot) * 512 + lane * 8) = pack8(a, b);
    }
  }
}

// ---------------- fused main kernel ----------------
// Block = 128 tokens of one expert, 4 waves; wave w owns m-range [32w, 32w+32).
// X frags live in VGPRs for the whole block. Per chunk (32 h values):
//   stage1 (K=32): hacc_hl = W1 . X^T for hl=0,1 (16 MFMA32)
//   gelu+pack:     a8[mt] = pack8(gelu4(hl0), gelu4(hl1))  == sigma-ordered
//                  K32 A-frag (position 8q+j holds h=sigma_q(j))
//   stage2 (K=32): oacc[mt][ot] += a8[mt] . W2frag (16 MFMA32, sigma-packed)
// All MFMA are now the native 16x16x32 op (4.85 cyc measured); round-7
// counters implied the legacy 16x16x16_1k cost ~21 cyc and dominated the
// MFMA pipe (MfmaUtil 30% at 135us with known instruction counts).
//
// Regs: (256,4) cap = 128 unified = 64 arch + 64 AGPR(oacc). r7 compiled to
// exactly 64 arch; this body is restructured (2-batch af reads, gelu hl0
// before hl1 load, 2-batch bfr) to stay near that. Tripwire: WRITE_SIZE
// >> 131MB means spill -> revert to (256,3).
__global__ __launch_bounds__(256, 4) void moe_fused(
    const float* __restrict__ X, const ushort* __restrict__ W1F,
    const ushort* __restrict__ W2F, float* __restrict__ Out) {
  __shared__ __align__(16) ushort W1s[2][4096];  // chunk: 2 htiles x 4 ks x 512
  __shared__ __align__(16) ushort W2s[2][4096];  // chunk: 8 ot x 64 lanes x 8

  const int tid  = threadIdx.x;
  const int lane = tid & 63;
  const int wid  = tid >> 6;
  const int q    = lane >> 4;
  const int l16  = lane & 15;

  // XCD swizzle: grid 2048 = 8 XCDs x 256 blocks (round-robin assumption).
  const int bid  = blockIdx.x;
  const int wk   = ((bid & 7) << 8) | (bid >> 3);
  const int e    = wk >> 4;
  const int tile = wk & 15;

  const float* Xe  = X + ((size_t)e * NT + (size_t)tile * 128) * DIN;
  const ushort* W1e = W1F + (size_t)e * 65536;
  const ushort* W2e = W2F + (size_t)e * 65536;
  float* Oe = Out + ((size_t)e * NT + (size_t)tile * 128) * DOUT;

  // ---- load this wave's X fragments into registers (once) ----
  s8v xf[2][4];
#pragma unroll
  for (int mt = 0; mt < 2; ++mt) {
#pragma unroll
    for (int ks = 0; ks < 4; ++ks) {
      const float* p = Xe + (size_t)(wid * 32 + mt * 16 + l16) * DIN + ks * 32 + q * 8;
      float4 v0 = *(const float4*)p;
      float4 v1 = *(const float4*)(p + 4);
      xf[mt][ks] = pack8(v0, v1);
    }
  }

  const f4v zero4 = {0.0f, 0.0f, 0.0f, 0.0f};
  f4v oacc[2][8];
#pragma unroll
  for (int mt = 0; mt < 2; ++mt)
#pragma unroll
    for (int ot = 0; ot < 8; ++ot) oacc[mt][ot] = zero4;

  // issue 4 global_load_lds per thread for one chunk (2x W1 + 2x W2)
  auto stage = [&](int chunk, int b) {
    const ushort* g1 = W1e + chunk * 4096;
    const ushort* g2 = W2e + chunk * 4096;
#pragma unroll
    for (int i = 0; i < 2; ++i) {
      int u = i * 256 + tid;
      GLOAD16(g1 + u * 8, &W1s[b][u * 8]);
      GLOAD16(g2 + u * 8, &W2s[b][u * 8]);
    }
  };

  asm volatile("" ::: "memory");

  // ---- prologue: chunk 0 into buf 0 ----
  stage(0, 0);

  for (int c = 0; c < 16; ++c) {
    const int buf = c & 1;
    WAIT_VM(0);   // retire my chunk-c loads (issued a full chunk ago; L2-hot)
    BAR();        // chunk-c LDS visible everywhere; buf^1 free (WAR)
    if (c < 15) stage(c + 1, buf ^ 1);

    // ---- stage 1, hl=0: K=32 over d ----
    f4v h0[2]; h0[0] = zero4; h0[1] = zero4;
#pragma unroll
    for (int kp = 0; kp < 2; ++kp) {
      s8v af0 = *(const s8v*)&W1s[buf][(kp * 2 + 0) * 512 + lane * 8];
      s8v af1 = *(const s8v*)&W1s[buf][(kp * 2 + 1) * 512 + lane * 8];
      __builtin_amdgcn_s_setprio(1);
      h0[0] = MFMA32(af0, xf[0][kp * 2 + 0], h0[0]);
      h0[1] = MFMA32(af0, xf[1][kp * 2 + 0], h0[1]);
      h0[0] = MFMA32(af1, xf[0][kp * 2 + 1], h0[0]);
      h0[1] = MFMA32(af1, xf[1][kp * 2 + 1], h0[1]);
      __builtin_amdgcn_s_setprio(0);
    }
    // gelu hl=0 now (frees h0 before h1 goes live — reg pressure)
    float4 ga0 = gelu4(h0[0]);
    float4 ga1 = gelu4(h0[1]);

    // ---- stage 1, hl=1 ----
    f4v h1[2]; h1[0] = zero4; h1[1] = zero4;
#pragma unroll
    for (int kp = 0; kp < 2; ++kp) {
      s8v af0 = *(const s8v*)&W1s[buf][(4 + kp * 2 + 0) * 512 + lane * 8];
      s8v af1 = *(const s8v*)&W1s[buf][(4 + kp * 2 + 1) * 512 + lane * 8];
      __builtin_amdgcn_s_setprio(1);
      h1[0] = MFMA32(af0, xf[0][kp * 2 + 0], h1[0]);
      h1[1] = MFMA32(af0, xf[1][kp * 2 + 0], h1[1]);
      h1[0] = MFMA32(af1, xf[0][kp * 2 + 1], h1[0]);
      h1[1] = MFMA32(af1, xf[1][kp * 2 + 1], h1[1]);
      __builtin_amdgcn_s_setprio(0);
    }

    // ---- pack: a8 position 8q+j -> j<4: hl0 (h=4q+j), j>=4: hl1 (h=16+4q+j-4)
    s8v a8_0 = pack8(ga0, gelu4(h1[0]));
    s8v a8_1 = pack8(ga1, gelu4(h1[1]));

    // ---- stage 2: K=32, 8 o-tiles, sigma-packed W2 frags ----
#pragma unroll
    for (int op = 0; op < 4; ++op) {
      s8v b0 = *(const s8v*)&W2s[buf][(op * 2 + 0) * 512 + lane * 8];
      s8v b1 = *(const s8v*)&W2s[buf][(op * 2 + 1) * 512 + lane * 8];
      __builtin_amdgcn_s_setprio(1);
      oacc[0][op * 2 + 0] = MFMA32(a8_0, b0, oacc[0][op * 2 + 0]);
      oacc[1][op * 2 + 0] = MFMA32(a8_1, b0, oacc[1][op * 2 + 0]);
      oacc[0][op * 2 + 1] = MFMA32(a8_0, b1, oacc[0][op * 2 + 1]);
      oacc[1][op * 2 + 1] = MFMA32(a8_1, b1, oacc[1][op * 2 + 1]);
      __builtin_amdgcn_s_setprio(0);
    }
  }

  // ---- epilogue: D layout col=o=l16, row m = 4q + r (C/D map is K-indep) ----
#pragma unroll
  for (int mt = 0; mt < 2; ++mt) {
    const int mb = wid * 32 + mt * 16 + 4 * q;
#pragma unroll
    for (int ot = 0; ot < 8; ++ot) {
      float* p = Oe + (size_t)mb * DOUT + ot * 16 + l16;
      p[0 * DOUT] = oacc[mt][ot][0];
      p[1 * DOUT] = oacc[mt][ot][1];
      p[2 * DOUT] = oacc[mt][ot][2];
      p[3 * DOUT] = oacc[mt][ot][3];
    }
  }
}

extern "C" void kernel_launch(void* const* d_in, const int* in_sizes, int n_in,
                              void* d_out, int out_size, void* d_ws, size_t ws_size,
                              hipStream_t stream) {
  const float* X  = (const float*)d_in[0];
  const float* W1 = (const float*)d_in[1];
  const float* W2 = (const float*)d_in[2];
  float* Out = (float*)d_out;

  ushort* W1F = (ushort*)d_ws;                             // 128 KB/expert = 16.8 MB
  ushort* W2F = (ushort*)d_ws + (size_t)NE * 65536;        // 128 KB/expert = 16.8 MB

  pack_weights<<<W1_BLOCKS + W2_BLOCKS, 256, 0, stream>>>(W1, W2, W1F, W2F);
  moe_fused<<<NE * (NT / 128), 256, 0, stream>>>(X, W1F, W2F, Out);
}

// Round 11
// 338.202 us; speedup vs baseline: 1.0978x; 1.0978x over previous
//
#include <hip/hip_runtime.h>
#include <hip/hip_bf16.h>
#include <stdint.h>

typedef __attribute__((ext_vector_type(8))) short s8v;   // 8 bf16 = K32 MFMA A/B frag
typedef __attribute__((ext_vector_type(4))) float f4v;   // MFMA C/D frag

#define NE   128
#define NT   2048
#define DIN  128
#define DH   512
#define DOUT 128

#define MFMA32(a,b,c) __builtin_amdgcn_mfma_f32_16x16x32_bf16(a,b,c,0,0,0)
// Stage2 uses native K32 MFMA with a sigma-permuted W2 pack (r9). The r9
// counters confirmed the MFMA-pipe win (MfmaUtil 30->15.8% at equal FLOPs)
// but (256,4) spilled ~60B/thread (WRITE 131->164MB, FETCH 82->111MB).
// r10: revert to (256,3) — the pre-committed tripwire action.

// async global->LDS, 16B per lane; LDS dest must be wave-uniform base + lane*16
#define GLOAD16(g,l) __builtin_amdgcn_global_load_lds( \
    (const __attribute__((address_space(1))) void*)(g), \
    (__attribute__((address_space(3))) void*)(l), 16, 0, 0)

#define WAIT_VM(N) asm volatile("s_waitcnt vmcnt(" #N ")" ::: "memory")
// raw barrier (no implicit vmcnt(0) drain, unlike __syncthreads)
#define BAR() do { asm volatile("" ::: "memory"); \
                   __builtin_amdgcn_s_barrier();  \
                   asm volatile("" ::: "memory"); } while (0)

__device__ __forceinline__ __hip_bfloat162 pk2(float a, float b) {
  float2 t; t.x = a; t.y = b;
  return __float22bfloat162_rn(t);
}

__device__ __forceinline__ s8v pack8(float4 a, float4 b) {
  union { s8v v; __hip_bfloat162 h[4]; } u;
  u.h[0] = pk2(a.x, a.y); u.h[1] = pk2(a.z, a.w);
  u.h[2] = pk2(b.x, b.y); u.h[3] = pk2(b.z, b.w);
  return u.v;
}

// gelu(x) = x * sigmoid(x*(1.5957691 + 0.07135481*x^2))  (tanh-form rewritten)
__device__ __forceinline__ float gelu_f(float x) {
  float x2 = x * x;
  float p  = __builtin_fmaf(x2, 0.07135481f, 1.5957691f);
  float e  = __expf(-x * p);
  return x * __builtin_amdgcn_rcpf(1.0f + e);
}

__device__ __forceinline__ float4 gelu4(f4v v) {
  float4 r;
  r.x = gelu_f(v[0]); r.y = gelu_f(v[1]);
  r.z = gelu_f(v[2]); r.w = gelu_f(v[3]);
  return r;
}

// ---------------- merged prep kernel ----------------
// Grid = NE*4 (W1 path) + NE*16 (W2 path).
//
// W1 path: block=(e,ks) reads rows d in [32ks,32ks+32) contiguously,
// transposes through LDS in 4 h-chunks of 128.
// W1F layout: [e][ht 0..31][ks 0..3][lane 0..63][8 bf16]; frag value j =
// W1[e][d = ks*32 + (lane>>4)*8 + j][h = ht*16 + (lane&15)]
//
// W2 path (K32 stage2): block=(e,ct) reads rows h in [32ct,32ct+32)
// contiguously. Output is a K32 B-frag with the sigma-permuted k order:
// position k = 8q+j holds h = 32ct + sigma_q(j),
//   sigma_q(j) = (j<4) ? 4q+j : 16+4q+(j-4)
// which is exactly where stage1's gelu outputs sit per lane (hl=0 gives
// h=4q+r, hl=1 gives h=16+4q+r). sigma is a bijection on [0,32) and both
// MFMA operands use the same permutation, so the contraction is exact.
// W2F layout: [e][ct 0..15][ot 0..7][lane 0..63][8 bf16]; frag value j =
// W2[e][h = 32ct + sigma_q(j)][o = ot*16 + (lane&15)]
#define W1_BLOCKS (NE * 4)
#define W2_BLOCKS (NE * 16)
__global__ __launch_bounds__(256) void pack_weights(
    const float* __restrict__ W1, const float* __restrict__ W2,
    ushort* __restrict__ W1F, ushort* __restrict__ W2F) {
  __shared__ __align__(16) float T[32 * 132];   // 16.9 KB, shared by both paths
  const int tid = threadIdx.x;
  const int lane = tid & 63, wid = tid >> 6;
  const int q = lane >> 4, l16 = lane & 15;

  if ((int)blockIdx.x < W1_BLOCKS) {
    const int e = blockIdx.x >> 2, ks = blockIdx.x & 3;
    const float* We = W1 + (size_t)e * (DIN * DH) + (size_t)(ks * 32) * DH;
    const int r = tid >> 3, c0 = (tid & 7) * 16;   // contiguous 64B/thread
    for (int hc = 0; hc < 4; ++hc) {
      if (hc) __syncthreads();                    // T reuse: reads done before rewrite
      const float* src = We + (size_t)r * DH + hc * 128 + c0;
      float4 v0 = *(const float4*)(src + 0);
      float4 v1 = *(const float4*)(src + 4);
      float4 v2 = *(const float4*)(src + 8);
      float4 v3 = *(const float4*)(src + 12);
      float* t = &T[r * 132 + c0];
      *(float4*)(t + 0) = v0; *(float4*)(t + 4)  = v1;
      *(float4*)(t + 8) = v2; *(float4*)(t + 12) = v3;
      __syncthreads();
#pragma unroll
      for (int i = 0; i < 2; ++i) {
        const int htl = wid + 4 * i;              // 0..7
        const int ht  = hc * 8 + htl;
        float g[8];
#pragma unroll
        for (int j = 0; j < 8; ++j) g[j] = T[(8 * q + j) * 132 + 16 * htl + l16];
        float4 a; a.x = g[0]; a.y = g[1]; a.z = g[2]; a.w = g[3];
        float4 b; b.x = g[4]; b.y = g[5]; b.z = g[6]; b.w = g[7];
        *(s8v*)(W1F + ((((size_t)e * 32 + ht) * 4) + ks) * 512 + lane * 8) = pack8(a, b);
      }
    }
  } else {
    const int bb = (int)blockIdx.x - W1_BLOCKS;
    const int e = bb >> 4, ct = bb & 15;
    const int r = tid >> 3, c0 = (tid & 7) * 16;   // contiguous 64B/thread
    const float* src = W2 + (size_t)e * (DH * DOUT) + (size_t)(ct * 32 + r) * DOUT + c0;
    float4 v0 = *(const float4*)(src + 0);
    float4 v1 = *(const float4*)(src + 4);
    float4 v2 = *(const float4*)(src + 8);
    float4 v3 = *(const float4*)(src + 12);
    float* t = &T[r * 132 + c0];
    *(float4*)(t + 0) = v0; *(float4*)(t + 4)  = v1;
    *(float4*)(t + 8) = v2; *(float4*)(t + 12) = v3;
    __syncthreads();
#pragma unroll
    for (int i = 0; i < 2; ++i) {
      const int ot = wid + 4 * i;                 // 0..7
      float g[8];
#pragma unroll
      for (int j = 0; j < 8; ++j) {
        const int sig = (j < 4) ? (4 * q + j) : (16 + 4 * q + (j - 4));
        g[j] = T[sig * 132 + ot * 16 + l16];
      }
      float4 a; a.x = g[0]; a.y = g[1]; a.z = g[2]; a.w = g[3];
      float4 b; b.x = g[4]; b.y = g[5]; b.z = g[6]; b.w = g[7];
      *(s8v*)(W2F + (((size_t)e * 16 + ct) * 8 + ot) * 512 + lane * 8) = pack8(a, b);
    }
  }
}

// ---------------- fused main kernel ----------------
// Block = 128 tokens of one expert, 4 waves; wave w owns m-range [32w, 32w+32).
// X frags live in VGPRs for the whole block. Per chunk (32 h values):
//   stage1 (K=32): hacc_hl = W1 . X^T for hl=0,1 (16 MFMA32)
//   gelu+pack:     a8[mt] = pack8(gelu4(hl0), gelu4(hl1))  == sigma-ordered
//                  K32 A-frag (position 8q+j holds h=sigma_q(j))
//   stage2 (K=32): oacc[mt][ot] += a8[mt] . W2frag (16 MFMA32, sigma-packed)
//
// Launch bounds history (unified VGPR+AGPR file, oacc = 64 AGPR fixed):
//   (256,5) r4: cap 102 -> oacc spilled, 4.2GB scratch, 6x slower.
//   (256,4) r9: cap 128 -> K32 body needs ~140, ~60B/thread spill
//               (WRITE 131->164MB, FETCH 82->111MB), 173us.
//   (256,3) r10: cap ~170 >= ~140 need. 3 blocks/CU x 32KB LDS = 96KB.
// Tripwire stands: WRITE_SIZE must be ~131MB, FETCH ~82MB.
__global__ __launch_bounds__(256, 3) void moe_fused(
    const float* __restrict__ X, const ushort* __restrict__ W1F,
    const ushort* __restrict__ W2F, float* __restrict__ Out) {
  __shared__ __align__(16) ushort W1s[2][4096];  // chunk: 2 htiles x 4 ks x 512
  __shared__ __align__(16) ushort W2s[2][4096];  // chunk: 8 ot x 64 lanes x 8

  const int tid  = threadIdx.x;
  const int lane = tid & 63;
  const int wid  = tid >> 6;
  const int q    = lane >> 4;
  const int l16  = lane & 15;

  // XCD swizzle: grid 2048 = 8 XCDs x 256 blocks (round-robin assumption).
  const int bid  = blockIdx.x;
  const int wk   = ((bid & 7) << 8) | (bid >> 3);
  const int e    = wk >> 4;
  const int tile = wk & 15;

  const float* Xe  = X + ((size_t)e * NT + (size_t)tile * 128) * DIN;
  const ushort* W1e = W1F + (size_t)e * 65536;
  const ushort* W2e = W2F + (size_t)e * 65536;
  float* Oe = Out + ((size_t)e * NT + (size_t)tile * 128) * DOUT;

  // ---- load this wave's X fragments into registers (once) ----
  s8v xf[2][4];
#pragma unroll
  for (int mt = 0; mt < 2; ++mt) {
#pragma unroll
    for (int ks = 0; ks < 4; ++ks) {
      const float* p = Xe + (size_t)(wid * 32 + mt * 16 + l16) * DIN + ks * 32 + q * 8;
      float4 v0 = *(const float4*)p;
      float4 v1 = *(const float4*)(p + 4);
      xf[mt][ks] = pack8(v0, v1);
    }
  }

  const f4v zero4 = {0.0f, 0.0f, 0.0f, 0.0f};
  f4v oacc[2][8];
#pragma unroll
  for (int mt = 0; mt < 2; ++mt)
#pragma unroll
    for (int ot = 0; ot < 8; ++ot) oacc[mt][ot] = zero4;

  // issue 4 global_load_lds per thread for one chunk (2x W1 + 2x W2)
  auto stage = [&](int chunk, int b) {
    const ushort* g1 = W1e + chunk * 4096;
    const ushort* g2 = W2e + chunk * 4096;
#pragma unroll
    for (int i = 0; i < 2; ++i) {
      int u = i * 256 + tid;
      GLOAD16(g1 + u * 8, &W1s[b][u * 8]);
      GLOAD16(g2 + u * 8, &W2s[b][u * 8]);
    }
  };

  asm volatile("" ::: "memory");

  // ---- prologue: chunk 0 into buf 0 ----
  stage(0, 0);

  for (int c = 0; c < 16; ++c) {
    const int buf = c & 1;
    WAIT_VM(0);   // retire my chunk-c loads (issued a full chunk ago; L2-hot)
    BAR();        // chunk-c LDS visible everywhere; buf^1 free (WAR)
    if (c < 15) stage(c + 1, buf ^ 1);

    // ---- stage 1, hl=0: K=32 over d ----
    f4v h0[2]; h0[0] = zero4; h0[1] = zero4;
#pragma unroll
    for (int kp = 0; kp < 2; ++kp) {
      s8v af0 = *(const s8v*)&W1s[buf][(kp * 2 + 0) * 512 + lane * 8];
      s8v af1 = *(const s8v*)&W1s[buf][(kp * 2 + 1) * 512 + lane * 8];
      __builtin_amdgcn_s_setprio(1);
      h0[0] = MFMA32(af0, xf[0][kp * 2 + 0], h0[0]);
      h0[1] = MFMA32(af0, xf[1][kp * 2 + 0], h0[1]);
      h0[0] = MFMA32(af1, xf[0][kp * 2 + 1], h0[0]);
      h0[1] = MFMA32(af1, xf[1][kp * 2 + 1], h0[1]);
      __builtin_amdgcn_s_setprio(0);
    }
    // gelu hl=0 now (frees h0 before h1 goes live — reg pressure)
    float4 ga0 = gelu4(h0[0]);
    float4 ga1 = gelu4(h0[1]);

    // ---- stage 1, hl=1 ----
    f4v h1[2]; h1[0] = zero4; h1[1] = zero4;
#pragma unroll
    for (int kp = 0; kp < 2; ++kp) {
      s8v af0 = *(const s8v*)&W1s[buf][(4 + kp * 2 + 0) * 512 + lane * 8];
      s8v af1 = *(const s8v*)&W1s[buf][(4 + kp * 2 + 1) * 512 + lane * 8];
      __builtin_amdgcn_s_setprio(1);
      h1[0] = MFMA32(af0, xf[0][kp * 2 + 0], h1[0]);
      h1[1] = MFMA32(af0, xf[1][kp * 2 + 0], h1[1]);
      h1[0] = MFMA32(af1, xf[0][kp * 2 + 1], h1[0]);
      h1[1] = MFMA32(af1, xf[1][kp * 2 + 1], h1[1]);
      __builtin_amdgcn_s_setprio(0);
    }

    // ---- pack: a8 position 8q+j -> j<4: hl0 (h=4q+j), j>=4: hl1 (h=16+4q+j-4)
    s8v a8_0 = pack8(ga0, gelu4(h1[0]));
    s8v a8_1 = pack8(ga1, gelu4(h1[1]));

    // ---- stage 2: K=32, 8 o-tiles, sigma-packed W2 frags ----
#pragma unroll
    for (int op = 0; op < 4; ++op) {
      s8v b0 = *(const s8v*)&W2s[buf][(op * 2 + 0) * 512 + lane * 8];
      s8v b1 = *(const s8v*)&W2s[buf][(op * 2 + 1) * 512 + lane * 8];
      __builtin_amdgcn_s_setprio(1);
      oacc[0][op * 2 + 0] = MFMA32(a8_0, b0, oacc[0][op * 2 + 0]);
      oacc[1][op * 2 + 0] = MFMA32(a8_1, b0, oacc[1][op * 2 + 0]);
      oacc[0][op * 2 + 1] = MFMA32(a8_0, b1, oacc[0][op * 2 + 1]);
      oacc[1][op * 2 + 1] = MFMA32(a8_1, b1, oacc[1][op * 2 + 1]);
      __builtin_amdgcn_s_setprio(0);
    }
  }

  // ---- epilogue: D layout col=o=l16, row m = 4q + r (C/D map is K-indep) ----
#pragma unroll
  for (int mt = 0; mt < 2; ++mt) {
    const int mb = wid * 32 + mt * 16 + 4 * q;
#pragma unroll
    for (int ot = 0; ot < 8; ++ot) {
      float* p = Oe + (size_t)mb * DOUT + ot * 16 + l16;
      p[0 * DOUT] = oacc[mt][ot][0];
      p[1 * DOUT] = oacc[mt][ot][1];
      p[2 * DOUT] = oacc[mt][ot][2];
      p[3 * DOUT] = oacc[mt][ot][3];
    }
  }
}

extern "C" void kernel_launch(void* const* d_in, const int* in_sizes, int n_in,
                              void* d_out, int out_size, void* d_ws, size_t ws_size,
                              hipStream_t stream) {
  const float* X  = (const float*)d_in[0];
  const float* W1 = (const float*)d_in[1];
  const float* W2 = (const float*)d_in[2];
  float* Out = (float*)d_out;

  ushort* W1F = (ushort*)d_ws;                             // 128 KB/expert = 16.8 MB
  ushort* W2F = (ushort*)d_ws + (size_t)NE * 65536;        // 128 KB/expert = 16.8 MB

  pack_weights<<<W1_BLOCKS + W2_BLOCKS, 256, 0, stream>>>(W1, W2, W1F, W2F);
  moe_fused<<<NE * (NT / 128), 256, 0, stream>>>(X, W1F, W2F, Out);
}